// Round 4
// baseline (405.191 us; speedup 1.0000x reference)
//
#include <hip/hip_runtime.h>
#include <hip/hip_bf16.h>
#include <math.h>

#define BB 16
#define NN 512
#define DD 256
#define KK 12

typedef __bf16 bf16x8 __attribute__((ext_vector_type(8)));
typedef __bf16 bf16x4 __attribute__((ext_vector_type(4)));
typedef float  f32x4  __attribute__((ext_vector_type(4)));

// workspace layout (bytes)
#define WS_WM     0              // wm[b,n] = w*mask_n, f32, 32KB
#define WS_NCNT   32768          // ncnt[b,m] int32 neighbor counts (atomic), 32KB
#define WS_MASKBF 65536          // maskbf[b,n] bf16 0/1, 16KB
#define WS_NODEBF 81920          // node bf16 [B][N][D] (unscaled, self term), 4MB
#define WS_NODET  4276224        // node_t bf16 [B][D][N], scaled by wm, 4MB
#define WS_WKBF   8470528        // Wk bf16 [K][D][D], 1.5MB
#define WS_WSBF   10043392       // Ws bf16 [D][D], 128KB
#define WS_T      10174464       // T bf16 [B][N][K][D]  (b,m,k,e), 50MB

// ---------------------------------------------------------------- k1: w, all_weight, wm, maskbf, node_bf16
__global__ __launch_bounds__(256) void k1_prep(const float* __restrict__ node,
        const float* __restrict__ Ww, const float* __restrict__ bw,
        const int* __restrict__ node_mask,
        float* __restrict__ wm, __bf16* __restrict__ maskbf,
        __bf16* __restrict__ node_bf, float* __restrict__ all_w) {
    int t = threadIdx.x;
    int lane = t & 63;
    int row = blockIdx.x * 4 + (t >> 6);           // b*N + n
    const float4 nv = *(const float4*)(node + (size_t)row * DD + lane * 4);
    const float4 wv = *(const float4*)(Ww + lane * 4);
    float dot = nv.x*wv.x + nv.y*wv.y + nv.z*wv.z + nv.w*wv.w;
    #pragma unroll
    for (int off = 32; off > 0; off >>= 1) dot += __shfl_xor(dot, off);
    float w = 1.0f / (1.0f + expf(-(dot + bw[0])));
    int mk = node_mask[row];
    if (lane == 0) {
        wm[row]     = w * (float)mk;
        all_w[row]  = w;
        maskbf[row] = (__bf16)(float)mk;
    }
    bf16x4 nb = {(__bf16)nv.x, (__bf16)nv.y, (__bf16)nv.z, (__bf16)nv.w};
    *(bf16x4*)(node_bf + (size_t)row * DD + lane * 4) = nb;
}

// ---------------------------------------------------------------- k1b: Wk, Ws -> bf16
__global__ __launch_bounds__(256) void k1b_convert(const float* __restrict__ Wk,
        const float* __restrict__ Ws, __bf16* __restrict__ Wk_bf, __bf16* __restrict__ Ws_bf) {
    const int KDD = KK * DD * DD;
    int idx = (blockIdx.x * 256 + threadIdx.x) * 4;
    if (idx < KDD) {
        float4 v = *(const float4*)(Wk + idx);
        bf16x4 o = {(__bf16)v.x, (__bf16)v.y, (__bf16)v.z, (__bf16)v.w};
        *(bf16x4*)(Wk_bf + idx) = o;
    } else {
        int j = idx - KDD;
        if (j < DD * DD) {
            float4 v = *(const float4*)(Ws + j);
            bf16x4 o = {(__bf16)v.x, (__bf16)v.y, (__bf16)v.z, (__bf16)v.w};
            *(bf16x4*)(Ws_bf + j) = o;
        }
    }
}

// ---------------------------------------------------------------- k2: node fp32 [B][N][D] -> node_t bf16 [B][D][N] scaled by wm[b,n]
__global__ __launch_bounds__(256) void k2_transpose(const float* __restrict__ node,
        const float* __restrict__ wm, __bf16* __restrict__ dst) {
    __shared__ float tile[64][65];
    int bx = blockIdx.x;
    int b = bx >> 5; int rest = bx & 31; int nt = rest >> 2; int dt = rest & 3;
    int n0 = nt * 64, d0 = dt * 64;
    int t = threadIdx.x;
    #pragma unroll
    for (int i = 0; i < 16; i++) {
        int idx = i * 256 + t;
        int n = idx >> 6, d = idx & 63;
        tile[n][d] = node[((size_t)(b * NN + n0 + n)) * DD + d0 + d];
    }
    __syncthreads();
    #pragma unroll
    for (int i = 0; i < 16; i++) {
        int idx = i * 256 + t;
        int d = idx >> 6, n = idx & 63;
        float w = wm[b * NN + n0 + n];
        dst[((size_t)(b * DD + d0 + d)) * NN + n0 + n] = (__bf16)(tile[n][d] * w);
    }
}

// ---------------------------------------------------------------- k4: T[b,m,k,e] = sum_n g[m,n](n!=m) * wnode_t[b,e,n]
// Full 64x512 A-strip staged contiguously (1 barrier), then barrier-free MFMA sweep.
// Counts computed on the matrix pipe via an extra mask-column MFMA.
__global__ __launch_bounds__(256) void k4_stageA(const int* __restrict__ graphs,
        const __bf16* __restrict__ maskbf, const __bf16* __restrict__ node_t,
        __bf16* __restrict__ T, int* __restrict__ ncnt) {
    __shared__ __align__(16) __bf16 Abf[64][520];
    __shared__ float cntp[4][64];
    int bx = blockIdx.x;
    int b  = bx & 15;                  // XCD swizzle: bx%8 -> b in {x, x+8}
    int mt = (bx >> 4) & 7;
    int k  = bx >> 7;
    int m0 = mt * 64;
    int t = threadIdx.x;
    int lane = t & 63;
    int wave = t >> 6;
    int q = lane >> 4;
    int l16 = lane & 15;
    int e0 = wave * 64;

    // ---- phase 1: stage full 64x512 strip, contiguous linear loads, 8-deep MLP
    const int4* gbase = (const int4*)(graphs + ((size_t)((k * BB + b) * NN + m0)) * NN);
    int colbase = (t * 4) & 511;       // fixed per thread
    int rowpar  = t >> 7;              // 0 or 1
    #pragma unroll
    for (int jj = 0; jj < 4; jj++) {
        int4 g[8];
        #pragma unroll
        for (int u = 0; u < 8; u++)
            g[u] = gbase[(jj * 8 + u) * 256 + t];
        #pragma unroll
        for (int u = 0; u < 8; u++) {
            int row = 2 * (jj * 8 + u) + rowpar;
            unsigned p0 = (unsigned)g[u].x | ((unsigned)g[u].y << 16);
            unsigned p1 = (unsigned)g[u].z | ((unsigned)g[u].w << 16);
            unsigned drel = (unsigned)(m0 + row - colbase);
            if (drel < 2u)      p0 &= ~(0xFFFFu << (16 * drel));
            else if (drel < 4u) p1 &= ~(0xFFFFu << (16 * (drel - 2)));
            uint2 st; st.x = p0 * 0x3F80u; st.y = p1 * 0x3F80u;
            *(uint2*)&Abf[row][colbase] = st;
        }
    }
    __syncthreads();

    // ---- phase 2: barrier-free MFMA sweep over 16 n-chunks of 32
    f32x4 acc[4][4];
    #pragma unroll
    for (int i = 0; i < 4; i++)
        #pragma unroll
        for (int j = 0; j < 4; j++) acc[i][j] = (f32x4){0.f, 0.f, 0.f, 0.f};
    f32x4 accC[4];
    #pragma unroll
    for (int i = 0; i < 4; i++) accC[i] = (f32x4){0.f, 0.f, 0.f, 0.f};
    int cw0 = wave * 4;                // this wave's count kk-subrange

    #pragma unroll
    for (int kk = 0; kk < 16; kk++) {
        int n0c = kk * 32;
        bf16x8 af[4], bfr[4];
        #pragma unroll
        for (int fm = 0; fm < 4; fm++)
            af[fm] = *(const bf16x8*)&Abf[fm * 16 + l16][n0c + q * 8];
        #pragma unroll
        for (int fd = 0; fd < 4; fd++)
            bfr[fd] = *(const bf16x8*)(node_t +
                ((size_t)(b * DD + e0 + fd * 16 + l16)) * NN + n0c + q * 8);
        #pragma unroll
        for (int fm = 0; fm < 4; fm++)
            #pragma unroll
            for (int fd = 0; fd < 4; fd++)
                acc[fm][fd] = __builtin_amdgcn_mfma_f32_16x16x32_bf16(
                    af[fm], bfr[fd], acc[fm][fd], 0, 0, 0);
        // count MFMA: B = mask in column 0 only (wave-uniform condition)
        if (kk >= cw0 && kk < cw0 + 4) {
            bf16x8 bfm = (bf16x8){0,0,0,0,0,0,0,0};
            if (l16 == 0)
                bfm = *(const bf16x8*)(maskbf + b * NN + n0c + q * 8);
            #pragma unroll
            for (int fm = 0; fm < 4; fm++)
                accC[fm] = __builtin_amdgcn_mfma_f32_16x16x32_bf16(
                    af[fm], bfm, accC[fm], 0, 0, 0);
        }
    }

    // ---- counts: LDS partial, reduce, one atomic per row
    if (l16 == 0) {
        #pragma unroll
        for (int fm = 0; fm < 4; fm++)
            #pragma unroll
            for (int r = 0; r < 4; r++)
                cntp[wave][fm * 16 + q * 4 + r] = accC[fm][r];
    }
    __syncthreads();
    if (t < 64) {
        float c = cntp[0][t] + cntp[1][t] + cntp[2][t] + cntp[3][t];
        atomicAdd(&ncnt[b * NN + m0 + t], (int)(c + 0.5f));
    }

    // ---- store T bf16 in [b][m][k][e]. C/D: col=lane&15, row=(lane>>4)*4+reg
    #pragma unroll
    for (int fm = 0; fm < 4; fm++)
        #pragma unroll
        for (int fd = 0; fd < 4; fd++) {
            int col = e0 + fd * 16 + l16;
            #pragma unroll
            for (int r = 0; r < 4; r++) {
                int m = m0 + fm * 16 + q * 4 + r;
                T[((size_t)((b * NN + m) * KK + k)) * DD + col] = (__bf16)acc[fm][fd][r];
            }
        }
}

// ---------------------------------------------------------------- k5: LDS-free register GEMM
// out[b,m,d] = relu( s[b,m] * sum_{k,e} T[b,m,k,e] Wk[k,d,e] + sum_e node[b,m,e] Ws[d,e] + bs[d] )
__global__ __launch_bounds__(256) void k5_stageB(const __bf16* __restrict__ T,
        const __bf16* __restrict__ Wk_bf, const __bf16* __restrict__ node_bf,
        const __bf16* __restrict__ Ws_bf, const float* __restrict__ bs,
        const int* __restrict__ ncnt, const int* __restrict__ node_mask,
        float* __restrict__ out) {
    __shared__ float redbuf[64][65];
    int bx = blockIdx.x;
    int b = bx & 15;                   // XCD swizzle
    int mt = (bx >> 4) & 7;
    int dt = bx >> 7;
    int m0 = mt * 64, d0 = dt * 64;
    int t = threadIdx.x;
    int lane = t & 63;
    int wave = t >> 6;
    int q = lane >> 4;
    int l16 = lane & 15;
    int ew = wave * 64;                // wave's e-subrange

    f32x4 acc[4][4];
    #pragma unroll
    for (int i = 0; i < 4; i++)
        #pragma unroll
        for (int j = 0; j < 4; j++) acc[i][j] = (f32x4){0.f, 0.f, 0.f, 0.f};

    for (int k = 0; k < KK; k++) {
        #pragma unroll
        for (int kk = 0; kk < 2; kk++) {
            int eoff = ew + kk * 32 + q * 8;
            bf16x8 af[4], bfr[4];
            #pragma unroll
            for (int fm = 0; fm < 4; fm++)
                af[fm] = *(const bf16x8*)(T +
                    ((size_t)(b * NN + m0 + fm * 16 + l16)) * (KK * DD) + k * DD + eoff);
            #pragma unroll
            for (int fd = 0; fd < 4; fd++)
                bfr[fd] = *(const bf16x8*)(Wk_bf +
                    ((size_t)(k * DD + d0 + fd * 16 + l16)) * DD + eoff);
            #pragma unroll
            for (int fm = 0; fm < 4; fm++)
                #pragma unroll
                for (int fd = 0; fd < 4; fd++)
                    acc[fm][fd] = __builtin_amdgcn_mfma_f32_16x16x32_bf16(
                        af[fm], bfr[fd], acc[fm][fd], 0, 0, 0);
        }
    }

    // scale agg partial by s[b,m] (linear => per-wave partial scaling exact)
    #pragma unroll
    for (int fm = 0; fm < 4; fm++) {
        #pragma unroll
        for (int r = 0; r < 4; r++) {
            int m = m0 + fm * 16 + q * 4 + r;
            int c = ncnt[b * NN + m];
            float s = (float)node_mask[b * NN + m] / (float)(c >= 1 ? c : 1);
            #pragma unroll
            for (int fd = 0; fd < 4; fd++) acc[fm][fd][r] *= s;
        }
    }

    // self round: + node @ Ws^T
    #pragma unroll
    for (int kk = 0; kk < 2; kk++) {
        int eoff = ew + kk * 32 + q * 8;
        bf16x8 af[4], bfr[4];
        #pragma unroll
        for (int fm = 0; fm < 4; fm++)
            af[fm] = *(const bf16x8*)(node_bf +
                ((size_t)(b * NN + m0 + fm * 16 + l16)) * DD + eoff);
        #pragma unroll
        for (int fd = 0; fd < 4; fd++)
            bfr[fd] = *(const bf16x8*)(Ws_bf +
                ((size_t)(d0 + fd * 16 + l16)) * DD + eoff);
        #pragma unroll
        for (int fm = 0; fm < 4; fm++)
            #pragma unroll
            for (int fd = 0; fd < 4; fd++)
                acc[fm][fd] = __builtin_amdgcn_mfma_f32_16x16x32_bf16(
                    af[fm], bfr[fd], acc[fm][fd], 0, 0, 0);
    }

    // deterministic phased cross-wave reduction
    for (int w = 0; w < 4; w++) {
        if (wave == w) {
            #pragma unroll
            for (int fm = 0; fm < 4; fm++)
                #pragma unroll
                for (int fd = 0; fd < 4; fd++) {
                    int dd2 = fd * 16 + l16;
                    #pragma unroll
                    for (int r = 0; r < 4; r++) {
                        int mm = fm * 16 + q * 4 + r;
                        if (w == 0) redbuf[mm][dd2] = acc[fm][fd][r];
                        else        redbuf[mm][dd2] += acc[fm][fd][r];
                    }
                }
        }
        __syncthreads();
    }

    // epilogue: + bs, relu, float4 stores
    int row = t >> 2;
    int c0 = (t & 3) * 16;
    #pragma unroll
    for (int j = 0; j < 4; j++) {
        int d = d0 + c0 + j * 4;
        float4 bv = *(const float4*)(bs + d);
        float4 v;
        v.x = fmaxf(redbuf[row][c0 + j * 4 + 0] + bv.x, 0.0f);
        v.y = fmaxf(redbuf[row][c0 + j * 4 + 1] + bv.y, 0.0f);
        v.z = fmaxf(redbuf[row][c0 + j * 4 + 2] + bv.z, 0.0f);
        v.w = fmaxf(redbuf[row][c0 + j * 4 + 3] + bv.w, 0.0f);
        *(float4*)(out + ((size_t)(b * NN + m0 + row)) * DD + d) = v;
    }
}

// ----------------------------------------------------------------
extern "C" void kernel_launch(void* const* d_in, const int* in_sizes, int n_in,
                              void* d_out, int out_size, void* d_ws, size_t ws_size,
                              hipStream_t stream) {
    const float* node      = (const float*)d_in[0];
    const float* Ww        = (const float*)d_in[1];
    const float* bw        = (const float*)d_in[2];
    const float* Ws        = (const float*)d_in[3];
    const float* bs        = (const float*)d_in[4];
    const float* Wk        = (const float*)d_in[5];
    const int*   node_mask = (const int*)d_in[6];
    const int*   graphs    = (const int*)d_in[7];
    float* out   = (float*)d_out;
    float* all_w = out + (size_t)BB * NN * DD;

    char* ws = (char*)d_ws;
    float*  wm      = (float*)(ws + WS_WM);
    int*    ncnt    = (int*)(ws + WS_NCNT);
    __bf16* maskbf  = (__bf16*)(ws + WS_MASKBF);
    __bf16* node_bf = (__bf16*)(ws + WS_NODEBF);
    __bf16* node_t  = (__bf16*)(ws + WS_NODET);
    __bf16* Wk_bf   = (__bf16*)(ws + WS_WKBF);
    __bf16* Ws_bf   = (__bf16*)(ws + WS_WSBF);
    __bf16* Tbuf    = (__bf16*)(ws + WS_T);

    hipMemsetAsync(ncnt, 0, BB * NN * sizeof(int), stream);
    k1_prep    <<<2048, 256, 0, stream>>>(node, Ww, bw, node_mask, wm, maskbf, node_bf, all_w);
    k1b_convert<<< 832, 256, 0, stream>>>(Wk, Ws, Wk_bf, Ws_bf);
    k2_transpose<<<512, 256, 0, stream>>>(node, wm, node_t);
    k4_stageA  <<<1536, 256, 0, stream>>>(graphs, maskbf, node_t, Tbuf, ncnt);
    k5_stageB  <<< 512, 256, 0, stream>>>(Tbuf, Wk_bf, node_bf, Ws_bf, bs, ncnt, node_mask, out);
}

// Round 5
// 354.844 us; speedup vs baseline: 1.1419x; 1.1419x over previous
//
#include <hip/hip_runtime.h>
#include <hip/hip_bf16.h>
#include <math.h>

#define BB 16
#define NN 512
#define DD 256
#define KK 12

typedef __bf16 bf16x8 __attribute__((ext_vector_type(8)));
typedef __bf16 bf16x4 __attribute__((ext_vector_type(4)));
typedef float  f32x4  __attribute__((ext_vector_type(4)));

// workspace layout (bytes)
#define WS_WM     0              // wm[b,n] = w*mask_n, f32, 32KB
#define WS_MASKBF 32768          // maskbf[b,n] bf16 0/1, 16KB
#define WS_NODEBF 49152          // node bf16 [B][N][D] (unscaled, self term), 4MB
#define WS_NODET  4243456        // node_t bf16 [B][D][N], scaled by wm, 4MB
#define WS_WKBF   8437760        // Wk bf16 [K][D][D], 1.5MB
#define WS_WSBF   10010624       // Ws bf16 [D][D], 128KB

// ---------------------------------------------------------------- k1: w, all_weight, wm, maskbf, node_bf16
__global__ __launch_bounds__(256) void k1_prep(const float* __restrict__ node,
        const float* __restrict__ Ww, const float* __restrict__ bw,
        const int* __restrict__ node_mask,
        float* __restrict__ wm, __bf16* __restrict__ maskbf,
        __bf16* __restrict__ node_bf, float* __restrict__ all_w) {
    int t = threadIdx.x;
    int lane = t & 63;
    int row = blockIdx.x * 4 + (t >> 6);           // b*N + n
    const float4 nv = *(const float4*)(node + (size_t)row * DD + lane * 4);
    const float4 wv = *(const float4*)(Ww + lane * 4);
    float dot = nv.x*wv.x + nv.y*wv.y + nv.z*wv.z + nv.w*wv.w;
    #pragma unroll
    for (int off = 32; off > 0; off >>= 1) dot += __shfl_xor(dot, off);
    float w = 1.0f / (1.0f + expf(-(dot + bw[0])));
    int mk = node_mask[row];
    if (lane == 0) {
        wm[row]     = w * (float)mk;
        all_w[row]  = w;
        maskbf[row] = (__bf16)(float)mk;
    }
    bf16x4 nb = {(__bf16)nv.x, (__bf16)nv.y, (__bf16)nv.z, (__bf16)nv.w};
    *(bf16x4*)(node_bf + (size_t)row * DD + lane * 4) = nb;
}

// ---------------------------------------------------------------- k1b: Wk, Ws -> bf16
__global__ __launch_bounds__(256) void k1b_convert(const float* __restrict__ Wk,
        const float* __restrict__ Ws, __bf16* __restrict__ Wk_bf, __bf16* __restrict__ Ws_bf) {
    const int KDD = KK * DD * DD;
    int idx = (blockIdx.x * 256 + threadIdx.x) * 4;
    if (idx < KDD) {
        float4 v = *(const float4*)(Wk + idx);
        bf16x4 o = {(__bf16)v.x, (__bf16)v.y, (__bf16)v.z, (__bf16)v.w};
        *(bf16x4*)(Wk_bf + idx) = o;
    } else {
        int j = idx - KDD;
        if (j < DD * DD) {
            float4 v = *(const float4*)(Ws + j);
            bf16x4 o = {(__bf16)v.x, (__bf16)v.y, (__bf16)v.z, (__bf16)v.w};
            *(bf16x4*)(Ws_bf + j) = o;
        }
    }
}

// ---------------------------------------------------------------- k2: node fp32 [B][N][D] -> node_t bf16 [B][D][N] scaled by wm[b,n]
__global__ __launch_bounds__(256) void k2_transpose(const float* __restrict__ node,
        const float* __restrict__ wm, __bf16* __restrict__ dst) {
    __shared__ float tile[64][65];
    int bx = blockIdx.x;
    int b = bx >> 5; int rest = bx & 31; int nt = rest >> 2; int dt = rest & 3;
    int n0 = nt * 64, d0 = dt * 64;
    int t = threadIdx.x;
    #pragma unroll
    for (int i = 0; i < 16; i++) {
        int idx = i * 256 + t;
        int n = idx >> 6, d = idx & 63;
        tile[n][d] = node[((size_t)(b * NN + n0 + n)) * DD + d0 + d];
    }
    __syncthreads();
    #pragma unroll
    for (int i = 0; i < 16; i++) {
        int idx = i * 256 + t;
        int d = idx >> 6, n = idx & 63;
        float w = wm[b * NN + n0 + n];
        dst[((size_t)(b * DD + d0 + d)) * NN + n0 + n] = (__bf16)(tile[n][d] * w);
    }
}

// ---------------------------------------------------------------- k45: fused stageA+stageB
// Per block: batch b, 32-row m-tile, all 256 d.
// out[b,m,d] = relu( s[b,m] * Σ_k Σ_e (Σ_n g_k[m,n] wnode[n,e]) Wk[k,d,e] + Σ_e node[m,e] Ws[d,e] + bs[d] )
// T tile lives only in LDS; counts via mask-column MFMA, block-local reduce (no atomics).
__global__ __launch_bounds__(512, 2) void k45_fused(const int* __restrict__ graphs,
        const int* __restrict__ node_mask, const __bf16* __restrict__ maskbf,
        const __bf16* __restrict__ node_t, const __bf16* __restrict__ node_bf,
        const __bf16* __restrict__ Wk_bf, const __bf16* __restrict__ Ws_bf,
        const float* __restrict__ bs, float* __restrict__ out) {
    __shared__ __align__(16) __bf16 Abf[32][520];   // 33.3 KB adjacency strip (bf16 0/1)
    __shared__ __align__(16) __bf16 Tk[32][264];    // 16.9 KB per-k T tile
    __shared__ float cntp[8][32];
    __shared__ float sm[32];
    int bx = blockIdx.x;
    int b  = (bx & 7) + 8 * ((bx >> 3) & 1);        // XCD-local b: each XCD sees b=x, x+8
    int mt = bx >> 4;
    int m0 = mt * 32;
    int t = threadIdx.x;
    int lane = t & 63;
    int w = t >> 6;                                  // wave 0..7
    int q = lane >> 4;
    int l16 = lane & 15;
    int esub = w * 32;                               // wave's e-range in stage A
    int dsub = w * 32;                               // wave's d-range in stage B

    int crow = t >> 7;                               // convert: row parity 0..3
    int ccol = (t & 127) * 4;                        // convert: int32-column base

    f32x4 accO[2][2];
    #pragma unroll
    for (int i = 0; i < 2; i++)
        #pragma unroll
        for (int j = 0; j < 2; j++) accO[i][j] = (f32x4){0.f, 0.f, 0.f, 0.f};
    f32x4 accC[2];
    accC[0] = (f32x4){0.f, 0.f, 0.f, 0.f};
    accC[1] = (f32x4){0.f, 0.f, 0.f, 0.f};

    // preamble: issue strip 0 loads (whole 64 KB strip in flight per block)
    int4 g[8];
    {
        const int4* gb = (const int4*)(graphs + ((size_t)(b * NN + m0)) * NN);
        #pragma unroll
        for (int u = 0; u < 8; u++) g[u] = gb[u * 512 + t];
    }

    #pragma unroll 1
    for (int k = 0; k < KK; k++) {
        // ---- convert strip k (regs -> bf16 LDS), diag cleared
        #pragma unroll
        for (int u = 0; u < 8; u++) {
            int row = u * 4 + crow;
            unsigned p0 = (unsigned)g[u].x | ((unsigned)g[u].y << 16);
            unsigned p1 = (unsigned)g[u].z | ((unsigned)g[u].w << 16);
            unsigned drel = (unsigned)(m0 + row - ccol);
            if (drel < 2u)      p0 &= ~(0xFFFFu << (16 * drel));
            else if (drel < 4u) p1 &= ~(0xFFFFu << (16 * (drel - 2)));
            uint2 st; st.x = p0 * 0x3F80u; st.y = p1 * 0x3F80u;
            *(uint2*)&Abf[row][ccol] = st;
        }
        __syncthreads();                             // Abf ready; prev stage-B done with Tk

        // ---- issue next strip (in flight through stage A)
        if (k < KK - 1) {
            const int4* gb = (const int4*)(graphs + ((size_t)(((k + 1) * BB + b) * NN + m0)) * NN);
            #pragma unroll
            for (int u = 0; u < 8; u++) g[u] = gb[u * 512 + t];
        }

        // ---- stage A: T_k[m, e-sub] = Σ_n A[m,n] * wnode[n,e]
        f32x4 accT[2][2];
        #pragma unroll
        for (int i = 0; i < 2; i++)
            #pragma unroll
            for (int j = 0; j < 2; j++) accT[i][j] = (f32x4){0.f, 0.f, 0.f, 0.f};
        #pragma unroll
        for (int kk = 0; kk < 16; kk++) {
            int n0c = kk * 32;
            bf16x8 af[2], bfr[2];
            #pragma unroll
            for (int fm = 0; fm < 2; fm++)
                af[fm] = *(const bf16x8*)&Abf[fm * 16 + l16][n0c + q * 8];
            #pragma unroll
            for (int fd = 0; fd < 2; fd++)
                bfr[fd] = *(const bf16x8*)(node_t +
                    ((size_t)(b * DD + esub + fd * 16 + l16)) * NN + n0c + q * 8);
            #pragma unroll
            for (int fm = 0; fm < 2; fm++)
                #pragma unroll
                for (int fd = 0; fd < 2; fd++)
                    accT[fm][fd] = __builtin_amdgcn_mfma_f32_16x16x32_bf16(
                        af[fm], bfr[fd], accT[fm][fd], 0, 0, 0);
            // count MFMA: wave w covers chunks {2w, 2w+1}; col0 of D = Σ_n A[m,n]*mask[n]
            if ((kk >> 1) == w) {
                bf16x8 bfm = (bf16x8){0,0,0,0,0,0,0,0};
                if (l16 == 0)
                    bfm = *(const bf16x8*)(maskbf + b * NN + n0c + q * 8);
                accC[0] = __builtin_amdgcn_mfma_f32_16x16x32_bf16(af[0], bfm, accC[0], 0, 0, 0);
                accC[1] = __builtin_amdgcn_mfma_f32_16x16x32_bf16(af[1], bfm, accC[1], 0, 0, 0);
            }
        }
        // ---- T_k -> LDS bf16 (C/D layout: col=l16, row=q*4+r)
        #pragma unroll
        for (int fm = 0; fm < 2; fm++)
            #pragma unroll
            for (int fd = 0; fd < 2; fd++) {
                int col = esub + fd * 16 + l16;
                #pragma unroll
                for (int r = 0; r < 4; r++)
                    Tk[fm * 16 + q * 4 + r][col] = (__bf16)accT[fm][fd][r];
            }
        __syncthreads();                             // Tk ready; Abf free for next convert

        // ---- stage B: accO[m, d-sub] += Σ_e T_k[m,e] * Wk[k,d,e]
        #pragma unroll
        for (int ee = 0; ee < 8; ee++) {
            int e0c = ee * 32;
            bf16x8 afT[2], bw2[2];
            #pragma unroll
            for (int fm = 0; fm < 2; fm++)
                afT[fm] = *(const bf16x8*)&Tk[fm * 16 + l16][e0c + q * 8];
            #pragma unroll
            for (int fd = 0; fd < 2; fd++)
                bw2[fd] = *(const bf16x8*)(Wk_bf +
                    ((size_t)(k * DD + dsub + fd * 16 + l16)) * DD + e0c + q * 8);
            #pragma unroll
            for (int fm = 0; fm < 2; fm++)
                #pragma unroll
                for (int fd = 0; fd < 2; fd++)
                    accO[fm][fd] = __builtin_amdgcn_mfma_f32_16x16x32_bf16(
                        afT[fm], bw2[fd], accO[fm][fd], 0, 0, 0);
        }
    }

    // ---- counts: block-local reduce, s[m] = mask_m / max(1, cnt)
    if (l16 == 0) {
        #pragma unroll
        for (int fm = 0; fm < 2; fm++)
            #pragma unroll
            for (int r = 0; r < 4; r++)
                cntp[w][fm * 16 + q * 4 + r] = accC[fm][r];
    }
    __syncthreads();
    if (t < 32) {
        float c = 0.0f;
        #pragma unroll
        for (int w8 = 0; w8 < 8; w8++) c += cntp[w8][t];
        int mk = node_mask[b * NN + m0 + t];
        sm[t] = (float)mk / (c >= 0.5f ? c : 1.0f);
    }
    __syncthreads();

    // scale aggregate (linear => exact), then add self term on top
    #pragma unroll
    for (int fm = 0; fm < 2; fm++)
        #pragma unroll
        for (int r = 0; r < 4; r++) {
            float s = sm[fm * 16 + q * 4 + r];
            #pragma unroll
            for (int fd = 0; fd < 2; fd++) accO[fm][fd][r] *= s;
        }

    // ---- self: accO += node @ Ws^T
    #pragma unroll
    for (int ee = 0; ee < 8; ee++) {
        int e0c = ee * 32;
        bf16x8 afS[2], bwS[2];
        #pragma unroll
        for (int fm = 0; fm < 2; fm++)
            afS[fm] = *(const bf16x8*)(node_bf +
                ((size_t)(b * NN + m0 + fm * 16 + l16)) * DD + e0c + q * 8);
        #pragma unroll
        for (int fd = 0; fd < 2; fd++)
            bwS[fd] = *(const bf16x8*)(Ws_bf +
                ((size_t)(dsub + fd * 16 + l16)) * DD + e0c + q * 8);
        #pragma unroll
        for (int fm = 0; fm < 2; fm++)
            #pragma unroll
            for (int fd = 0; fd < 2; fd++)
                accO[fm][fd] = __builtin_amdgcn_mfma_f32_16x16x32_bf16(
                    afS[fm], bwS[fd], accO[fm][fd], 0, 0, 0);
    }

    // ---- epilogue: + bs, relu, store f32
    #pragma unroll
    for (int fm = 0; fm < 2; fm++)
        #pragma unroll
        for (int fd = 0; fd < 2; fd++) {
            int d = dsub + fd * 16 + l16;
            float bsv = bs[d];
            #pragma unroll
            for (int r = 0; r < 4; r++) {
                int m = m0 + fm * 16 + q * 4 + r;
                float v = accO[fm][fd][r] + bsv;
                out[((size_t)(b * NN + m)) * DD + d] = fmaxf(v, 0.0f);
            }
        }
}

// ----------------------------------------------------------------
extern "C" void kernel_launch(void* const* d_in, const int* in_sizes, int n_in,
                              void* d_out, int out_size, void* d_ws, size_t ws_size,
                              hipStream_t stream) {
    const float* node      = (const float*)d_in[0];
    const float* Ww        = (const float*)d_in[1];
    const float* bw        = (const float*)d_in[2];
    const float* Ws        = (const float*)d_in[3];
    const float* bs        = (const float*)d_in[4];
    const float* Wk        = (const float*)d_in[5];
    const int*   node_mask = (const int*)d_in[6];
    const int*   graphs    = (const int*)d_in[7];
    float* out   = (float*)d_out;
    float* all_w = out + (size_t)BB * NN * DD;

    char* ws = (char*)d_ws;
    float*  wm      = (float*)(ws + WS_WM);
    __bf16* maskbf  = (__bf16*)(ws + WS_MASKBF);
    __bf16* node_bf = (__bf16*)(ws + WS_NODEBF);
    __bf16* node_t  = (__bf16*)(ws + WS_NODET);
    __bf16* Wk_bf   = (__bf16*)(ws + WS_WKBF);
    __bf16* Ws_bf   = (__bf16*)(ws + WS_WSBF);

    k1_prep    <<<2048, 256, 0, stream>>>(node, Ww, bw, node_mask, wm, maskbf, node_bf, all_w);
    k1b_convert<<< 832, 256, 0, stream>>>(Wk, Ws, Wk_bf, Ws_bf);
    k2_transpose<<<512, 256, 0, stream>>>(node, wm, node_t);
    k45_fused  <<< 256, 512, 0, stream>>>(graphs, node_mask, maskbf, node_t, node_bf,
                                          Wk_bf, Ws_bf, bs, out);
}